// Round 1
// baseline (544.559 us; speedup 1.0000x reference)
//
#include <hip/hip_runtime.h>
#include <hip/hip_bf16.h>

#define B_ 32
#define S_ 4096
#define H_ 512
#define M_ (B_ * S_)   // 131072
#define L_ 2

typedef __bf16 bf16;
typedef bf16 bf16x8 __attribute__((ext_vector_type(8)));
typedef bf16 bf16x4 __attribute__((ext_vector_type(4)));
typedef float floatx4 __attribute__((ext_vector_type(4)));

__device__ inline bf16 f2b(float f) { return (bf16)f; }

__device__ inline float fast_tanh(float x) {
    float xc = fminf(15.0f, fmaxf(-15.0f, x));
    float e = __expf(2.0f * xc);
    return (e - 1.0f) * __builtin_amdgcn_rcpf(e + 1.0f);
}

// ---------------- kernel 0: convert W (H,H) fp32 -> bf16, same layout ----------------
__global__ __launch_bounds__(256) void convert_W(const float* __restrict__ W,
                                                 bf16* __restrict__ Wb) {
    int i = blockIdx.x * 256 + threadIdx.x;      // float4 index, total H*H/4
    float4 w = ((const float4*)W)[i];
    bf16x4 p = { f2b(w.x), f2b(w.y), f2b(w.z), f2b(w.w) };
    *(bf16x4*)(Wb + (size_t)i * 4) = p;
}

// ---------------- kernel 1: fused  scores[m] = sum_n tanh(out@W^T + b + hlast)[m,n] * v[n]
// M-tile = 64 rows per workgroup. A (64 x 512) staged once in LDS as bf16.
// Loop n-blocks of 128, k-chunks of 32 (one MFMA K-step per chunk).
// Wave layout: 4 waves = 2 m-halves x 2 n-halves; each wave: 2 m-tiles x 4 n-tiles.
#define MT 64
#define ASTRIDE 520   // 512 + 8 pad: row stride 1040B = 260 dw == 4 (mod 32) -> 2-way, free
#define WSTRIDE 40    // 32 + 8 pad: row stride 80B = 20 dw -> 2-way, free

__global__ __launch_bounds__(256, 2) void scores_kernel(
    const float* __restrict__ outT,   // (M, 512)
    const bf16*  __restrict__ Wb,     // (512, 512) row-major (o, h)
    const float* __restrict__ bias,   // (512)
    const float* __restrict__ hidden, // (L, B, 512)
    const float* __restrict__ v,      // (512)
    float* __restrict__ scores)       // (M)
{
    __shared__ bf16 Alds[MT * ASTRIDE];    // 66560 B
    __shared__ bf16 Wlds[128 * WSTRIDE];   // 10240 B   total 76800 B -> 2 blocks/CU

    const int tid   = threadIdx.x;
    const int wave  = tid >> 6;
    const int lane  = tid & 63;
    const int mhalf = wave >> 1;     // 0..1
    const int nhalf = wave & 1;      // 0..1
    const int q     = lane >> 4;     // quad 0..3
    const int l16   = lane & 15;

    const int m0    = blockIdx.x * MT;
    const int batch = m0 >> 12;      // m0 / S_

    // ---- stage A: 64 rows x 512 fp32 -> bf16 LDS (tile is contiguous in global)
    {
        const float4* src = (const float4*)(outT + (size_t)m0 * H_);
        #pragma unroll 4
        for (int it = 0; it < 32; ++it) {
            int idx = it * 256 + tid;          // float4 index in tile
            int r   = idx >> 7;                // 128 float4 per row
            int c4  = idx & 127;
            float4 f = src[idx];
            bf16x4 p = { f2b(f.x), f2b(f.y), f2b(f.z), f2b(f.w) };
            *(bf16x4*)&Alds[r * ASTRIDE + c4 * 4] = p;
        }
    }

    float score_acc[2][4];
    #pragma unroll
    for (int mt = 0; mt < 2; ++mt)
        #pragma unroll
        for (int r = 0; r < 4; ++r) score_acc[mt][r] = 0.0f;

    const int nwbase = nhalf * 64;   // wave's n offset inside the 128-wide n-block

    for (int nb = 0; nb < 4; ++nb) {
        floatx4 acc[2][4];
        #pragma unroll
        for (int mt = 0; mt < 2; ++mt)
            #pragma unroll
            for (int nt = 0; nt < 4; ++nt)
                acc[mt][nt] = (floatx4){0.f, 0.f, 0.f, 0.f};

        for (int kc = 0; kc < 16; ++kc) {
            __syncthreads();
            // stage W chunk: rows nb*128..+128, cols kc*32..+32 (16 bf16 per thread)
            {
                int r    = tid >> 1;
                int hcol = tid & 1;
                const bf16* gsrc = Wb + (size_t)(nb * 128 + r) * H_ + kc * 32 + hcol * 16;
                uint4 u0 = *(const uint4*)(gsrc);
                uint4 u1 = *(const uint4*)(gsrc + 8);
                bf16* dst = &Wlds[r * WSTRIDE + hcol * 16];
                *(uint4*)(dst)     = u0;
                *(uint4*)(dst + 8) = u1;
            }
            __syncthreads();

            // one K=32 MFMA step
            bf16x8 afrag[2], bfrag[4];
            const int kin = kc * 32 + q * 8;
            #pragma unroll
            for (int mt = 0; mt < 2; ++mt)
                afrag[mt] = *(const bf16x8*)&Alds[(mhalf * 32 + mt * 16 + l16) * ASTRIDE + kin];
            #pragma unroll
            for (int nt = 0; nt < 4; ++nt)
                bfrag[nt] = *(const bf16x8*)&Wlds[(nwbase + nt * 16 + l16) * WSTRIDE + q * 8];
            #pragma unroll
            for (int mt = 0; mt < 2; ++mt)
                #pragma unroll
                for (int nt = 0; nt < 4; ++nt)
                    acc[mt][nt] = __builtin_amdgcn_mfma_f32_16x16x32_bf16(
                        afrag[mt], bfrag[nt], acc[mt][nt], 0, 0, 0);
        }

        // epilogue for this n-block: tanh(acc + b + hlast) * v, accumulate per-row partials
        #pragma unroll
        for (int nt = 0; nt < 4; ++nt) {
            int n = nb * 128 + nwbase + nt * 16 + l16;
            float bias_n = bias[n] + hidden[(size_t)((L_ - 1) * B_ + batch) * H_ + n];
            float v_n = v[n];
            #pragma unroll
            for (int mt = 0; mt < 2; ++mt)
                #pragma unroll
                for (int r = 0; r < 4; ++r) {
                    float e = fast_tanh(acc[mt][nt][r] + bias_n);
                    score_acc[mt][r] += e * v_n;
                }
        }
    }

    // reduce partial scores across the 16 n-lanes of each quad; row = q*4 + r
    #pragma unroll
    for (int mt = 0; mt < 2; ++mt)
        #pragma unroll
        for (int r = 0; r < 4; ++r) {
            float s = score_acc[mt][r];
            s += __shfl_xor(s, 1);
            s += __shfl_xor(s, 2);
            s += __shfl_xor(s, 4);
            s += __shfl_xor(s, 8);
            score_acc[mt][r] = s;
        }
    if (l16 == 0) {
        #pragma unroll
        for (int mt = 0; mt < 2; ++mt)
            #pragma unroll
            for (int r = 0; r < 4; ++r) {
                int row = m0 + mhalf * 32 + mt * 16 + q * 4 + r;
                atomicAdd(&scores[row], score_acc[mt][r]);
            }
    }
}

// ---------------- kernel 2: softmax over S per batch ----------------
__global__ __launch_bounds__(256) void softmax_kernel(const float* __restrict__ scores,
                                                      float* __restrict__ attn) {
    __shared__ float red[4];
    int b = blockIdx.x, tid = threadIdx.x;
    const float* row = scores + (size_t)b * S_;
    float vals[16];
    float mx = -3.4e38f;
    #pragma unroll
    for (int i = 0; i < 16; ++i) { vals[i] = row[i * 256 + tid]; mx = fmaxf(mx, vals[i]); }
    #pragma unroll
    for (int off = 32; off >= 1; off >>= 1) mx = fmaxf(mx, __shfl_xor(mx, off));
    if ((tid & 63) == 0) red[tid >> 6] = mx;
    __syncthreads();
    mx = fmaxf(fmaxf(red[0], red[1]), fmaxf(red[2], red[3]));
    __syncthreads();
    float sum = 0.f;
    #pragma unroll
    for (int i = 0; i < 16; ++i) { vals[i] = __expf(vals[i] - mx); sum += vals[i]; }
    #pragma unroll
    for (int off = 32; off >= 1; off >>= 1) sum += __shfl_xor(sum, off);
    if ((tid & 63) == 0) red[tid >> 6] = sum;
    __syncthreads();
    float inv = 1.0f / (red[0] + red[1] + red[2] + red[3]);
    #pragma unroll
    for (int i = 0; i < 16; ++i) attn[(size_t)b * S_ + i * 256 + tid] = vals[i] * inv;
}

// ---------------- kernel 3: context[b,h] = sum_s attn[b,s] * out[b,s,h] ----------------
#define SCHUNK 128
__global__ __launch_bounds__(256) void context_kernel(const float* __restrict__ outT,
                                                      const float* __restrict__ attn,
                                                      float* __restrict__ ctx) {
    int b   = blockIdx.y;
    int s0  = blockIdx.x * SCHUNK;
    int tid = threadIdx.x;
    float2 acc = {0.f, 0.f};
    const float2* base = (const float2*)(outT + ((size_t)b * S_ + s0) * H_);
    const float*  arow = attn + (size_t)b * S_ + s0;
    #pragma unroll 4
    for (int s = 0; s < SCHUNK; ++s) {
        float a  = arow[s];
        float2 o = base[(size_t)s * 256 + tid];
        acc.x += a * o.x;
        acc.y += a * o.y;
    }
    float* c = ctx + (size_t)b * H_ + tid * 2;
    atomicAdd(c, acc.x);
    atomicAdd(c + 1, acc.y);
}

extern "C" void kernel_launch(void* const* d_in, const int* in_sizes, int n_in,
                              void* d_out, int out_size, void* d_ws, size_t ws_size,
                              hipStream_t stream) {
    const float* outT   = (const float*)d_in[0];  // (B,S,H)
    const float* hidden = (const float*)d_in[1];  // (L,B,H)
    const float* W      = (const float*)d_in[2];  // (H,H)
    const float* bias   = (const float*)d_in[3];  // (H)
    const float* v      = (const float*)d_in[4];  // (H)

    float* ctx    = (float*)d_out;                // (B,H) = 16384 floats
    float* attn   = (float*)d_out + B_ * H_;      // (B,S) = 131072 floats
    float* scores = (float*)d_ws;                 // M floats (512 KB)
    bf16*  Wb     = (bf16*)((char*)d_ws + (size_t)M_ * sizeof(float)); // 512 KB

    hipMemsetAsync(scores, 0, (size_t)M_ * sizeof(float), stream);
    hipMemsetAsync(ctx, 0, (size_t)B_ * H_ * sizeof(float), stream);

    convert_W<<<H_ * H_ / 4 / 256, 256, 0, stream>>>(W, Wb);
    scores_kernel<<<M_ / MT, 256, 0, stream>>>(outT, Wb, bias, hidden, v, scores);
    softmax_kernel<<<B_, 256, 0, stream>>>(scores, attn);
    context_kernel<<<dim3(S_ / SCHUNK, B_), 256, 0, stream>>>(outT, attn, ctx);
}